// Round 6
// baseline (647.806 us; speedup 1.0000x reference)
//
#include <hip/hip_runtime.h>
#include <hip/hip_cooperative_groups.h>

namespace cg = cooperative_groups;

// Problem constants
#define N_NODES 100000
#define N_EDGES 3200000
#define IN_CH   256
#define OUT_CH  128

// Deterministic two-pass counting sort (NO device-scope atomics anywhere).
#define BSH        5                        // bucket = src >> 5  (32 nodes)
#define BN         32                       // nodes per bucket
#define NBIN       3125                     // N_NODES / BN (exact)
#define NBLK1      256                      // stage-1 chunks == coop grid (1/CU)
#define EPB1       12500                    // edges per chunk (256*12500 = 3.2M exact)
#define ITER1      4                        // ceil(EPB1 / 4096)
#define NS1        (NBIN * NBLK1)           // 800,000 counters (div by 4)
#define SCAN_CHUNK 8192
#define NBLK_S1    ((NS1 + SCAN_CHUNK - 1) / SCAN_CHUNK)   // 98
#define SCAP       2048                     // sortf LDS staging capacity (records)
#define CBLK       256                      // coop grid blocks
#define CTHR       1024                     // coop block threads

// ---------------------------------------------------------------------------
// Workspace layout (bytes):
//   xwb    [N_NODES*OUT_CH] bf16 : 25,600,000
//   wbf    [128][256]       bf16 :     65,536   (W^T, n-major)
//   cntT   [NBLK1][NBIN]    i32  :  3,200,000   (chunk-major counts)
//   cntA   [NBIN][NBLK1]    i32  :  3,200,000   (bucket-major, scan order)
//   rpA    [NS1+1(+pad)]    i32  :  3,200,016   (scanned bases, bucket-major)
//   rpT    [NBLK1][NBIN]    i32  :  3,200,000   (bases, chunk-major for b1)
//   bsum   [256]            i32  :      1,024
//   rpn    [N_NODES+1(+pad)]i32  :    400,016   (node-major CSR row ptrs)
//   packed [N_EDGES]        int2 : 25,600,000   (node-sorted final CSR)
// total = 64,466,592  (ws_size >= 78,000,016 proven in R2)
// p1 (bucket-sorted stage-1 records, 25.6 MB) lives in d_out (51.2 MB) —
// dead before aggregate_kernel, which fully overwrites d_out.
// ---------------------------------------------------------------------------
#define OFF_XWB    0
#define OFF_WBF    25600000
#define OFF_CNTT   25665536
#define OFF_CNTA   28865536
#define OFF_RPA    32065536
#define OFF_RPT    35265552
#define OFF_BS     38465552
#define OFF_RPN    38466576
#define OFF_PACKED 38866592

typedef __attribute__((ext_vector_type(8))) short    bf8;   // 8 bf16 = 4 VGPRs
typedef __attribute__((ext_vector_type(4))) float    f4;    // C/D frag
typedef __attribute__((ext_vector_type(4))) unsigned uv4;   // 16B load vehicle

__device__ __forceinline__ unsigned f2bf(float f) {   // fp32 -> bf16 (RNE)
    unsigned u = __float_as_uint(f);
    return (u + 0x7fffu + ((u >> 16) & 1u)) >> 16;
}

__device__ __forceinline__ unsigned cvt_pk_bf16(float lo, float hi) {
    unsigned r;                                       // D[15:0]=bf16(lo), D[31:16]=bf16(hi)
    asm("v_cvt_pk_bf16_f32 %0, %1, %2" : "=v"(r) : "v"(lo), "v"(hi));
    return r;
}

// ---------------------------------------------------------------------------
// MFMA GEMM: xw = x @ W (bf16 inputs, fp32 accumulate, bf16 output).
// Wave tile = 16 rows x 128 cols (8 col-tiles of mfma_f32_16x16x32_bf16).
// ---------------------------------------------------------------------------
__global__ __launch_bounds__(256) void gemm_kernel(const float* __restrict__ x,
                                                   const unsigned short* __restrict__ wbf,
                                                   unsigned* __restrict__ xwb) {
    int wave = threadIdx.x >> 6;
    int lane = threadIdx.x & 63;
    int m = lane & 15;
    int q = lane >> 4;
    int r0 = blockIdx.x * 64 + wave * 16;

    int arow = r0 + m;
    if (arow >= N_NODES) arow = N_NODES - 1;     // clamp loads; stores guarded
    const float* xr = x + (long long)arow * IN_CH + q * 8;

    f4 acc[8];
#pragma unroll
    for (int ct = 0; ct < 8; ++ct) acc[ct] = (f4){0.f, 0.f, 0.f, 0.f};

#pragma unroll
    for (int ks = 0; ks < 8; ++ks) {             // k0 = ks*32
        float4 xa = *(const float4*)(xr + ks * 32);
        float4 xb = *(const float4*)(xr + ks * 32 + 4);
        uv4 au;
        au[0] = cvt_pk_bf16(xa.x, xa.y);
        au[1] = cvt_pk_bf16(xa.z, xa.w);
        au[2] = cvt_pk_bf16(xb.x, xb.y);
        au[3] = cvt_pk_bf16(xb.z, xb.w);
        bf8 a = __builtin_bit_cast(bf8, au);
#pragma unroll
        for (int ct = 0; ct < 8; ++ct) {
            uv4 u = *(const uv4*)&wbf[(ct * 16 + m) * 256 + ks * 32 + q * 8];
            bf8 b = __builtin_bit_cast(bf8, u);
            acc[ct] = __builtin_amdgcn_mfma_f32_16x16x32_bf16(a, b, acc[ct], 0, 0, 0);
        }
    }

#pragma unroll
    for (int ct = 0; ct < 8; ++ct) {
#pragma unroll
        for (int r = 0; r < 4; ++r) {
            float v = acc[ct][r];
            float p = __shfl_xor(v, 1, 64);
            unsigned wpk = cvt_pk_bf16(v, p);    // lo = even ch, hi = odd ch
            if (!(m & 1)) {
                int row = r0 + q * 4 + r;
                if (row < N_NODES)
                    xwb[row * 64 + ct * 8 + (m >> 1)] = wpk;
            }
        }
    }
}

// ---------------------------------------------------------------------------
// Cooperative preprocessing mega-kernel: replaces wcvt + h1 + transpose +
// scan_s1/s2/s3 + transpose + b1 + sortf (9 launches -> 1). 256 blocks x
// 1024 threads (1 block/CU, guaranteed co-resident), grid.sync() between
// phases. Every phase keeps full-GPU parallelism; LDS phases share a union.
// ---------------------------------------------------------------------------
union CoopLds {
    int lc[NBIN];                                   // h1 hist / b1 cursors (12.5 KB)
    int tp[32][33];                                 // transpose tile (4.2 KB)
    int ws[16];                                     // scan wave sums
    struct { int cnt[BN]; int cur[BN]; int2 buf[SCAP]; } sf;   // sortf (16.6 KB)
};

__global__ __launch_bounds__(1024) void coop_kernel(
    const float* __restrict__ w,    unsigned short* __restrict__ wbf,
    const int*   __restrict__ src,  const int* __restrict__ dst,
    const float* __restrict__ val,
    int* __restrict__ cntT, int* __restrict__ cntA,
    int* __restrict__ rpA,  int* __restrict__ rpT,
    int* __restrict__ bsum, int* __restrict__ rpn,
    int2* __restrict__ p1,  int2* __restrict__ packed)
{
    cg::grid_group grid = cg::this_grid();
    __shared__ CoopLds S;
    const int tid  = threadIdx.x;
    const int b    = blockIdx.x;
    const int lane = tid & 63;
    const int wid  = tid >> 6;
    const int e0   = b * EPB1;

    // ---- P0: wcvt  w[256][128] fp32 -> wbf[128][256] bf16 -----------------
    {
        int gid = b * CTHR + tid;
        if (gid < 32768) {
            int k = gid >> 7, n = gid & 127;
            wbf[n * 256 + k] = (unsigned short)f2bf(w[k * 128 + n]);
        }
    }

    // ---- P1: per-chunk bucket histogram (LDS atomics only) ----------------
    for (int i = tid; i < NBIN; i += CTHR) S.lc[i] = 0;
    __syncthreads();
#pragma unroll
    for (int k = 0; k < ITER1; ++k) {
        int i = e0 + k * 4096 + tid * 4;
        if (i < e0 + EPB1) {
            int4 s4 = *(const int4*)&src[i];
            atomicAdd(&S.lc[s4.x >> BSH], 1);
            atomicAdd(&S.lc[s4.y >> BSH], 1);
            atomicAdd(&S.lc[s4.z >> BSH], 1);
            atomicAdd(&S.lc[s4.w >> BSH], 1);
        }
    }
    __syncthreads();
    for (int i = tid; i < NBIN; i += CTHR) cntT[b * NBIN + i] = S.lc[i];
    grid.sync();

    // ---- P2: transpose cntT[256][3125] -> cntA[3125][256] -----------------
    {
        int tx = tid & 31, ty = tid >> 5;            // 32x32 = 1024 threads
        for (int t = b; t < 98 * 8; t += CBLK) {     // 98 col-tiles x 8 row-tiles
            int c0 = (t % 98) * 32, r0 = (t / 98) * 32;
            int r = r0 + ty, c = c0 + tx;
            S.tp[ty][tx] = (c < NBIN) ? cntT[r * NBIN + c] : 0;   // r<256 always
            __syncthreads();
            int c2 = c0 + ty, r2 = r0 + tx;
            if (c2 < NBIN) cntA[c2 * NBLK1 + r2] = S.tp[tx][ty];
            __syncthreads();
        }
    }
    grid.sync();

    // ---- P3: per-region sums (scan level 1): 98 regions of 8192 -----------
    if (b < NBLK_S1) {
        int acc = 0;
#pragma unroll
        for (int k = 0; k < 2; ++k) {
            int i0 = b * SCAN_CHUNK + k * 4096 + tid * 4;
            if (i0 < NS1) {
                int4 v = *(const int4*)&cntA[i0];
                acc += v.x + v.y + v.z + v.w;
            }
        }
#pragma unroll
        for (int off = 32; off; off >>= 1) acc += __shfl_down(acc, off, 64);
        if (lane == 0) S.ws[wid] = acc;
        __syncthreads();
        if (tid == 0) {
            int s = 0;
            for (int i = 0; i < 16; ++i) s += S.ws[i];
            bsum[b] = s;
        }
    }
    grid.sync();

    // ---- P4: exclusive scan of the 98 region sums (block 0, wave 0) -------
    if (b == 0 && wid == 0) {
        int v0 = (lane < NBLK_S1) ? bsum[lane] : 0;
        int v1 = (lane + 64 < NBLK_S1) ? bsum[lane + 64] : 0;
        int s0 = v0;
#pragma unroll
        for (int off = 1; off < 64; off <<= 1) {
            int t2 = __shfl_up(s0, off, 64);
            if (lane >= off) s0 += t2;
        }
        int tot0 = __shfl(s0, 63, 64);
        int s1 = v1;
#pragma unroll
        for (int off = 1; off < 64; off <<= 1) {
            int t2 = __shfl_up(s1, off, 64);
            if (lane >= off) s1 += t2;
        }
        int tot1 = __shfl(s1, 63, 64);
        if (lane < NBLK_S1) bsum[lane] = s0 - v0;
        if (lane + 64 < NBLK_S1) bsum[lane + 64] = tot0 + s1 - v1;
        if (lane == 0) {
            rpA[NS1] = tot0 + tot1;                  // == N_EDGES
            rpn[N_NODES] = tot0 + tot1;
        }
    }
    grid.sync();

    // ---- P5: scan within regions -> rpA (bucket-major bases) --------------
    if (b < NBLK_S1) {
        int carry = bsum[b];
        for (int k = 0; k < 2; ++k) {
            int i0 = b * SCAN_CHUNK + k * 4096 + tid * 4;
            int4 v = make_int4(0, 0, 0, 0);
            if (i0 < NS1) v = *(const int4*)&cntA[i0];
            int sum4 = v.x + v.y + v.z + v.w;
            int s = sum4;
#pragma unroll
            for (int off = 1; off < 64; off <<= 1) {
                int t2 = __shfl_up(s, off, 64);
                if (lane >= off) s += t2;
            }
            if (lane == 63) S.ws[wid] = s;
            __syncthreads();
            int woff = 0, wtot = 0;
            for (int i = 0; i < 16; ++i) {
                int x = S.ws[i];
                if (i < wid) woff += x;
                wtot += x;
            }
            int excl = carry + woff + (s - sum4);
            if (i0 < NS1)
                *(int4*)&rpA[i0] = make_int4(excl, excl + v.x, excl + v.x + v.y,
                                             excl + v.x + v.y + v.z);
            carry += wtot;
            __syncthreads();
        }
    }
    grid.sync();

    // ---- P6: transpose rpA[3125][256] -> rpT[256][3125] -------------------
    {
        int tx = tid & 31, ty = tid >> 5;
        for (int t = b; t < 98 * 8; t += CBLK) {     // 8 col-tiles x 98 row-tiles
            int c0 = (t % 8) * 32, r0 = (t / 8) * 32;
            int r = r0 + ty, c = c0 + tx;
            S.tp[ty][tx] = (r < NBIN) ? rpA[r * NBLK1 + c] : 0;   // c<256 always
            __syncthreads();
            int c2 = c0 + ty, r2 = r0 + tx;
            if (r2 < NBIN) rpT[c2 * NBIN + r2] = S.tp[tx][ty];
            __syncthreads();
        }
    }
    grid.sync();

    // ---- P7: deterministic scatter into bucket-major p1 (LDS cursors) -----
    // Record: x = dst | (src&31)<<17  (dst < 2^17), y = val bits.
    for (int i = tid; i < NBIN; i += CTHR) S.lc[i] = rpT[b * NBIN + i];
    __syncthreads();
#pragma unroll
    for (int k = 0; k < ITER1; ++k) {
        int i = e0 + k * 4096 + tid * 4;
        if (i < e0 + EPB1) {
            int4   s4 = *(const int4*)&src[i];
            int4   d4 = *(const int4*)&dst[i];
            float4 v4 = *(const float4*)&val[i];
            int p;
            p = atomicAdd(&S.lc[s4.x >> BSH], 1);
            p1[p] = make_int2(d4.x | ((s4.x & (BN - 1)) << 17), __float_as_int(v4.x));
            p = atomicAdd(&S.lc[s4.y >> BSH], 1);
            p1[p] = make_int2(d4.y | ((s4.y & (BN - 1)) << 17), __float_as_int(v4.y));
            p = atomicAdd(&S.lc[s4.z >> BSH], 1);
            p1[p] = make_int2(d4.z | ((s4.z & (BN - 1)) << 17), __float_as_int(v4.z));
            p = atomicAdd(&S.lc[s4.w >> BSH], 1);
            p1[p] = make_int2(d4.w | ((s4.w & (BN - 1)) << 17), __float_as_int(v4.w));
        }
    }
    grid.sync();

    // ---- P8: final per-bucket sort -> node-major packed + rpn -------------
    for (int bk = b; bk < NBIN; bk += CBLK) {
        int beg = rpA[bk * NBLK1];
        int end = rpA[(bk + 1) * NBLK1];             // bk==NBIN-1 hits rpA[NS1]
        int n = end - beg;

        if (tid < BN) S.sf.cnt[tid] = 0;
        __syncthreads();

        if (n <= SCAP) {
            for (int e = tid; e < n; e += CTHR) {
                int2 q = p1[beg + e];
                S.sf.buf[e] = q;
                atomicAdd(&S.sf.cnt[(q.x >> 17) & (BN - 1)], 1);
            }
        } else {
            for (int e = beg + tid; e < end; e += CTHR)
                atomicAdd(&S.sf.cnt[(p1[e].x >> 17) & (BN - 1)], 1);
        }
        __syncthreads();

        if (wid == 0) {                              // wave 0: scan 32 counts
            int c = (lane < BN) ? S.sf.cnt[lane] : 0;
            int v = c;
#pragma unroll
            for (int off = 1; off < BN; off <<= 1) {
                int t2 = __shfl_up(v, off, 64);
                if (lane >= off) v += t2;
            }
            if (lane < BN) {
                int excl = beg + v - c;
                S.sf.cur[lane] = excl;
                rpn[bk * BN + lane] = excl;          // NBIN*BN == N_NODES exactly
            }
        }
        __syncthreads();

        if (n <= SCAP) {
            for (int e = tid; e < n; e += CTHR) {
                int2 q = S.sf.buf[e];
                int p = atomicAdd(&S.sf.cur[(q.x >> 17) & (BN - 1)], 1);
                packed[p] = make_int2(q.x & 0x1FFFF, q.y);
            }
        } else {
            for (int e = beg + tid; e < end; e += CTHR) {
                int2 q = p1[e];
                int p = atomicAdd(&S.sf.cur[(q.x >> 17) & (BN - 1)], 1);
                packed[p] = make_int2(q.x & 0x1FFFF, q.y);
            }
        }
        __syncthreads();                             // before next bucket reuses LDS
    }
}

// ---------------------------------------------------------------------------
// Aggregate (R3 measured-best form): one node per wave; lanes cooperatively
// load packed records, broadcast via v_readlane, gathers in batches of 8.
// ---------------------------------------------------------------------------
__global__ __launch_bounds__(256) void aggregate_kernel(const int* __restrict__ rp,
                                                        const int2* __restrict__ packed,
                                                        const unsigned* __restrict__ xwb,
                                                        const float* __restrict__ bias,
                                                        float* __restrict__ out) {
    int node = blockIdx.x * 4 + (threadIdx.x >> 6);
    int lane = threadIdx.x & 63;
    float2 acc = *(const float2*)&bias[lane * 2];

    int beg = rp[node];
    int end = rp[node + 1];
    for (int t = beg; t < end; t += 64) {
        int2 rec = make_int2(0, 0);                  // dst=0, val=+0.0f (safe pad)
        if (t + lane < end) rec = packed[t + lane];
        int cnt = end - t; if (cnt > 64) cnt = 64;
        int cnt8 = (cnt + 7) & ~7;                   // pad lanes contribute 0
        for (int j = 0; j < cnt8; j += 8) {
            unsigned u[8]; float vv[8];
#pragma unroll
            for (int k = 0; k < 8; ++k) {
                int d  = __builtin_amdgcn_readlane(rec.x, j + k);
                vv[k]  = __int_as_float(__builtin_amdgcn_readlane(rec.y, j + k));
                u[k]   = xwb[d * 64 + lane];
            }
#pragma unroll
            for (int k = 0; k < 8; ++k) {
                acc.x += vv[k] * __uint_as_float(u[k] << 16);
                acc.y += vv[k] * __uint_as_float(u[k] & 0xffff0000u);
            }
        }
    }
    *(float2*)&out[(long long)node * OUT_CH + lane * 2] = acc;
}

extern "C" void kernel_launch(void* const* d_in, const int* in_sizes, int n_in,
                              void* d_out, int out_size, void* d_ws, size_t ws_size,
                              hipStream_t stream) {
    const float* x     = (const float*)d_in[0];
    const int*   esrc  = (const int*)d_in[1];
    const int*   edst  = (const int*)d_in[2];
    const float* evals = (const float*)d_in[3];
    const float* w     = (const float*)d_in[4];
    const float* bias  = (const float*)d_in[5];
    float* out = (float*)d_out;

    char* ws = (char*)d_ws;
    unsigned*       xwb    = (unsigned*)      (ws + OFF_XWB);
    unsigned short* wbf    = (unsigned short*)(ws + OFF_WBF);
    int*            cntT   = (int*)           (ws + OFF_CNTT);
    int*            cntA   = (int*)           (ws + OFF_CNTA);
    int*            rpA    = (int*)           (ws + OFF_RPA);
    int*            rpT    = (int*)           (ws + OFF_RPT);
    int*            bsum   = (int*)           (ws + OFF_BS);
    int*            rpn    = (int*)           (ws + OFF_RPN);
    int2*           packed = (int2*)          (ws + OFF_PACKED);
    int2*           p1     = (int2*)          d_out;   // scratch; dead before aggregate

    void* cargs[] = { (void*)&w, (void*)&wbf, (void*)&esrc, (void*)&edst,
                      (void*)&evals, (void*)&cntT, (void*)&cntA, (void*)&rpA,
                      (void*)&rpT, (void*)&bsum, (void*)&rpn, (void*)&p1,
                      (void*)&packed };
    hipLaunchCooperativeKernel((void*)coop_kernel, dim3(CBLK), dim3(CTHR),
                               cargs, 0, stream);
    gemm_kernel<<<(N_NODES + 63) / 64, 256, 0, stream>>>(x, wbf, xwb);
    aggregate_kernel<<<N_NODES / 4, 256, 0, stream>>>(rpn, packed, xwb, bias, out);
}

// Round 8
// 426.467 us; speedup vs baseline: 1.5190x; 1.5190x over previous
//
#include <hip/hip_runtime.h>

// Problem constants
#define N_NODES 100000
#define N_EDGES 3200000
#define IN_CH   256
#define OUT_CH  128

// Deterministic two-pass counting sort (no device atomics except lookback flags)
#define BSH        5                        // bucket = src >> 5  (32 nodes)
#define BN         32                       // nodes per bucket
#define NBIN       3125                     // N_NODES / BN (exact)
#define NBINP      3328                     // padded buckets = 256 * 13
#define BPT        13                       // buckets per scan tile
#define NBLK1      256                      // stage-1 chunks (1024-thr blocks, 1/CU)
#define EPB1       12500                    // edges per chunk (256*12500 = 3.2M exact)
#define ITER1      4                        // ceil(EPB1 / 4096)
#define SCAP       2048                     // agg LDS capacity (records per bucket)

// ---------------------------------------------------------------------------
// Workspace layout (bytes):
//   xwb  [N_NODES*OUT_CH] bf16 : 25,600,000
//   wbf  [128][256]       bf16 :     65,536   (W^T, n-major)
//   cntT [256][NBINP]     i32  :  3,407,872   (chunk-major counts, padded)
//   rpT  [256][NBINP]     i32  :  3,407,872   (scattered bases, chunk-major)
//   tot  [256]            i32  :      1,024   (lookback tile totals, -1 = not ready)
//   bb   [3336]           i32  :     13,344   (bucket bases in p1)
//   p1   [N_EDGES]        int2 : 25,600,000   (bucket-sorted records)
// total = 58,095,648  (ws_size >= 78,000,016 proven in R2)
// NOTE: p1 must NOT alias d_out — agg_fused reads p1 while writing out.
// ---------------------------------------------------------------------------
#define OFF_XWB  0
#define OFF_WBF  25600000
#define OFF_CNTT 25665536
#define OFF_RPT  29073408
#define OFF_TOT  32481280
#define OFF_BB   32482304
#define OFF_P1   32495648

typedef __attribute__((ext_vector_type(8))) short    bf8;   // 8 bf16 = 4 VGPRs
typedef __attribute__((ext_vector_type(4))) float    f4;    // C/D frag
typedef __attribute__((ext_vector_type(4))) unsigned uv4;   // 16B load vehicle

__device__ __forceinline__ unsigned f2bf(float f) {   // fp32 -> bf16 (RNE)
    unsigned u = __float_as_uint(f);
    return (u + 0x7fffu + ((u >> 16) & 1u)) >> 16;
}

__device__ __forceinline__ unsigned cvt_pk_bf16(float lo, float hi) {
    unsigned r;                                       // D[15:0]=bf16(lo), D[31:16]=bf16(hi)
    asm("v_cvt_pk_bf16_f32 %0, %1, %2" : "=v"(r) : "v"(lo), "v"(hi));
    return r;
}

// ---------------------------------------------------------------------------
// K1: wcvt + stage-1 histogram (fused). 256 blocks x 1024 threads.
// Also initializes the lookback flags (tot[] = -1).
// ---------------------------------------------------------------------------
__global__ __launch_bounds__(1024) void wcvt_h1_kernel(const float* __restrict__ w,
                                                       unsigned short* __restrict__ wbf,
                                                       const int* __restrict__ src,
                                                       int* __restrict__ cntT,
                                                       int* __restrict__ tot) {
    __shared__ int lc[NBIN];
    int tid = threadIdx.x, b = blockIdx.x;

    // wcvt: w[256][128] fp32 -> wbf[128][256] bf16 (blocks 0..31)
    int gid = b * 1024 + tid;
    if (gid < 32768) {
        int k = gid >> 7, n = gid & 127;
        wbf[n * 256 + k] = (unsigned short)f2bf(w[k * 128 + n]);
    }
    if (b == 0 && tid < 256) tot[tid] = -1;          // lookback sentinel

    for (int i = tid; i < NBIN; i += 1024) lc[i] = 0;
    __syncthreads();
    int e0 = b * EPB1;
#pragma unroll
    for (int k = 0; k < ITER1; ++k) {
        int i = e0 + k * 4096 + tid * 4;
        if (i < e0 + EPB1) {                          // EPB1 mult of 4 -> full int4 ok
            int4 s4 = *(const int4*)&src[i];
            atomicAdd(&lc[s4.x >> BSH], 1);
            atomicAdd(&lc[s4.y >> BSH], 1);
            atomicAdd(&lc[s4.z >> BSH], 1);
            atomicAdd(&lc[s4.w >> BSH], 1);
        }
    }
    __syncthreads();
    for (int i = tid; i < NBINP; i += 1024)
        cntT[b * NBINP + i] = (i < NBIN) ? lc[i] : 0;
}

// ---------------------------------------------------------------------------
// K2: MFMA GEMM xw = x @ W (unchanged R5 form).
// ---------------------------------------------------------------------------
__global__ __launch_bounds__(256) void gemm_kernel(const float* __restrict__ x,
                                                   const unsigned short* __restrict__ wbf,
                                                   unsigned* __restrict__ xwb) {
    int wave = threadIdx.x >> 6;
    int lane = threadIdx.x & 63;
    int m = lane & 15;
    int q = lane >> 4;
    int r0 = blockIdx.x * 64 + wave * 16;

    int arow = r0 + m;
    if (arow >= N_NODES) arow = N_NODES - 1;     // clamp loads; stores guarded
    const float* xr = x + (long long)arow * IN_CH + q * 8;

    f4 acc[8];
#pragma unroll
    for (int ct = 0; ct < 8; ++ct) acc[ct] = (f4){0.f, 0.f, 0.f, 0.f};

#pragma unroll
    for (int ks = 0; ks < 8; ++ks) {             // k0 = ks*32
        float4 xa = *(const float4*)(xr + ks * 32);
        float4 xb = *(const float4*)(xr + ks * 32 + 4);
        uv4 au;
        au[0] = cvt_pk_bf16(xa.x, xa.y);
        au[1] = cvt_pk_bf16(xa.z, xa.w);
        au[2] = cvt_pk_bf16(xb.x, xb.y);
        au[3] = cvt_pk_bf16(xb.z, xb.w);
        bf8 a = __builtin_bit_cast(bf8, au);
#pragma unroll
        for (int ct = 0; ct < 8; ++ct) {
            uv4 u = *(const uv4*)&wbf[(ct * 16 + m) * 256 + ks * 32 + q * 8];
            bf8 b = __builtin_bit_cast(bf8, u);
            acc[ct] = __builtin_amdgcn_mfma_f32_16x16x32_bf16(a, b, acc[ct], 0, 0, 0);
        }
    }

#pragma unroll
    for (int ct = 0; ct < 8; ++ct) {
#pragma unroll
        for (int r = 0; r < 4; ++r) {
            float v = acc[ct][r];
            float p = __shfl_xor(v, 1, 64);
            unsigned wpk = cvt_pk_bf16(v, p);    // lo = even ch, hi = odd ch
            if (!(m & 1)) {
                int row = r0 + q * 4 + r;
                if (row < N_NODES)
                    xwb[row * 64 + ct * 8 + (m >> 1)] = wpk;
            }
        }
    }
}

// ---------------------------------------------------------------------------
// K3: decoupled-lookback scan over the (bucket, chunk) count matrix.
// 256 tiles x 13 buckets; tile t scans its 3328 counts (bucket-major) in LDS,
// publishes its total (device-scope atomic, -1 sentinel), sums predecessors'
// totals in parallel, writes rpT[chunk][bucket] and bb[bucket]. Deterministic;
// no chaining (each tile publishes before looking back) -> no deadlock. Grid
// = 256 blocks <= 256 CUs, so all blocks are resident regardless of order.
// Replaces transpose + scan_s1/s2/s3 + transpose (5 launches -> 1).
// ---------------------------------------------------------------------------
__global__ __launch_bounds__(256) void scan_lb_kernel(const int* __restrict__ cntT,
                                                      int* __restrict__ tot,
                                                      int* __restrict__ rpT,
                                                      int* __restrict__ bb) {
    __shared__ int ldsv[BPT * 256];              // 3328 counts, f = b_local*256 + c
    __shared__ int wsum[4];
    __shared__ int red[4];
    __shared__ int sbase;
    int t = blockIdx.x, tid = threadIdx.x, lane = tid & 63, wid = tid >> 6;
    int b0 = t * BPT;

    // load: thread (=chunk c) reads its row's 13 buckets
#pragma unroll
    for (int j = 0; j < BPT; ++j)
        ldsv[j * 256 + tid] = cntT[tid * NBINP + b0 + j];
    __syncthreads();

    // per-thread serial sum over contiguous scan-order segment [tid*13, +13)
    int s = 0;
#pragma unroll
    for (int j = 0; j < BPT; ++j) s += ldsv[tid * BPT + j];

    // block inclusive scan of per-thread sums
    int v = s;
#pragma unroll
    for (int off = 1; off < 64; off <<= 1) {
        int tv = __shfl_up(v, off, 64);
        if (lane >= off) v += tv;
    }
    if (lane == 63) wsum[wid] = v;
    __syncthreads();
    int woff = (wid > 0 ? wsum[0] : 0) + (wid > 1 ? wsum[1] : 0) + (wid > 2 ? wsum[2] : 0);
    int T = wsum[0] + wsum[1] + wsum[2] + wsum[3];
    int excl = woff + v - s;                     // block-local exclusive prefix

    // publish tile total BEFORE lookback (no chaining -> no deadlock)
    if (tid == 0)
        __hip_atomic_store(&tot[t], T, __ATOMIC_RELEASE, __HIP_MEMORY_SCOPE_AGENT);

    // parallel lookback: thread tid reads tot[tid] for tid < t
    int pv = 0;
    if (tid < t) {
        int x;
        do {
            x = __hip_atomic_load(&tot[tid], __ATOMIC_ACQUIRE, __HIP_MEMORY_SCOPE_AGENT);
            if (x < 0) __builtin_amdgcn_s_sleep(8);
        } while (x < 0);
        pv = x;
    }
#pragma unroll
    for (int off = 32; off; off >>= 1) pv += __shfl_down(pv, off, 64);
    if (lane == 0) red[wid] = pv;
    __syncthreads();
    if (tid == 0) sbase = red[0] + red[1] + red[2] + red[3];
    __syncthreads();
    int base = sbase;

    // writeback: running global prefix through this thread's segment
    int run = base + excl;
#pragma unroll
    for (int j = 0; j < BPT; ++j) {
        int f = tid * BPT + j;
        int c = ldsv[f];
        ldsv[f] = run;
        run += c;
    }
    __syncthreads();

    // output: rpT[chunk][bucket] (thread = chunk), bb[bucket]
#pragma unroll
    for (int j = 0; j < BPT; ++j)
        rpT[tid * NBINP + b0 + j] = ldsv[j * 256 + tid];
    if (tid < BPT) bb[b0 + tid] = ldsv[tid * 256];
}

// ---------------------------------------------------------------------------
// K4: deterministic stage-1 scatter (unchanged logic; p1 in workspace).
// Record: x = dst | (src&31)<<17  (dst < 2^17), y = val bits.
// ---------------------------------------------------------------------------
__global__ __launch_bounds__(1024) void b1_kernel(const int* __restrict__ src,
                                                  const int* __restrict__ dst,
                                                  const float* __restrict__ val,
                                                  const int* __restrict__ rpT,
                                                  int2* __restrict__ p1) {
    __shared__ int lcur[NBIN];
    int tid = threadIdx.x;
    int e0 = blockIdx.x * EPB1;
    for (int i = tid; i < NBIN; i += 1024)
        lcur[i] = rpT[blockIdx.x * NBINP + i];
    __syncthreads();
#pragma unroll
    for (int k = 0; k < ITER1; ++k) {
        int i = e0 + k * 4096 + tid * 4;
        if (i < e0 + EPB1) {
            int4   s4 = *(const int4*)&src[i];
            int4   d4 = *(const int4*)&dst[i];
            float4 v4 = *(const float4*)&val[i];
            int p;
            p = atomicAdd(&lcur[s4.x >> BSH], 1);
            p1[p] = make_int2(d4.x | ((s4.x & (BN - 1)) << 17), __float_as_int(v4.x));
            p = atomicAdd(&lcur[s4.y >> BSH], 1);
            p1[p] = make_int2(d4.y | ((s4.y & (BN - 1)) << 17), __float_as_int(v4.y));
            p = atomicAdd(&lcur[s4.z >> BSH], 1);
            p1[p] = make_int2(d4.z | ((s4.z & (BN - 1)) << 17), __float_as_int(v4.z));
            p = atomicAdd(&lcur[s4.w >> BSH], 1);
            p1[p] = make_int2(d4.w | ((s4.w & (BN - 1)) << 17), __float_as_int(v4.w));
        }
    }
}

// ---------------------------------------------------------------------------
// K5: fused sort+aggregate. One block per 32-node bucket (3125 blocks x 256).
// Pass 1: 32-bin LDS histogram of the bucket's p1 segment; wave-0 scan ->
// per-node offsets. Pass 2: re-read p1, scatter records node-sorted into LDS.
// Then each of 4 waves aggregates 8 nodes from LDS (broadcast reads) with
// batch-8 independent xwb row gathers (R3 measured-best inner loop).
// Eliminates packed[] + rpn[] and the sortf launch entirely.
// ---------------------------------------------------------------------------
__global__ __launch_bounds__(256) void agg_fused_kernel(const int* __restrict__ bb,
                                                        const int2* __restrict__ p1,
                                                        const unsigned* __restrict__ xwb,
                                                        const float* __restrict__ bias,
                                                        float* __restrict__ out) {
    __shared__ int2 sbuf[SCAP];
    __shared__ int  lcnt[BN];
    __shared__ int  lcur[BN];
    __shared__ int  no[BN + 1];
    int bk = blockIdx.x, tid = threadIdx.x;
    int lane = tid & 63, wid = tid >> 6;
    int beg = bb[bk];
    int end = bb[bk + 1];
    int n = end - beg;

    float2 bb2 = *(const float2*)&bias[lane * 2];

    if (tid < BN) lcnt[tid] = 0;
    __syncthreads();

    if (n <= SCAP) {
        // pass 1: histogram
        for (int e = tid; e < n; e += 256)
            atomicAdd(&lcnt[(p1[beg + e].x >> 17) & (BN - 1)], 1);
        __syncthreads();
        // wave 0: exclusive scan of 32 counts -> node offsets (bucket-relative)
        if (wid == 0) {
            int c = (lane < BN) ? lcnt[lane] : 0;
            int v = c;
#pragma unroll
            for (int off = 1; off < BN; off <<= 1) {
                int tv = __shfl_up(v, off, 64);
                if (lane >= off) v += tv;
            }
            if (lane < BN) {
                no[lane] = v - c;
                lcur[lane] = v - c;
                if (lane == BN - 1) no[BN] = v;
            }
        }
        __syncthreads();
        // pass 2: node-sorted scatter into LDS
        for (int e = tid; e < n; e += 256) {
            int2 q = p1[beg + e];
            int p = atomicAdd(&lcur[(q.x >> 17) & (BN - 1)], 1);
            sbuf[p] = q;
        }
        __syncthreads();

        // aggregate: wave w handles nodes [w*8, w*8+8)
        for (int i = 0; i < 8; ++i) {
            int nl = wid * 8 + i;
            int e0 = no[nl], e1 = no[nl + 1];
            float2 acc = bb2;
            for (int e = e0; e < e1; e += 8) {
                unsigned u[8]; float vv[8];
#pragma unroll
                for (int k = 0; k < 8; ++k) {
                    int ii = e + k;
                    int2 q = (ii < e1) ? sbuf[ii] : make_int2(0, 0);
                    vv[k] = __int_as_float(q.y);
                    u[k]  = xwb[(q.x & 0x1FFFF) * 64 + lane];
                }
#pragma unroll
                for (int k = 0; k < 8; ++k) {
                    acc.x += vv[k] * __uint_as_float(u[k] << 16);
                    acc.y += vv[k] * __uint_as_float(u[k] & 0xffff0000u);
                }
            }
            *(float2*)&out[(long long)(bk * BN + nl) * OUT_CH + lane * 2] = acc;
        }
    } else {
        // fallback (statistically never: n <= 2048 for random graphs):
        // per node, scan the whole segment scalar-broadcast and filter.
        for (int i = 0; i < 8; ++i) {
            int nl = wid * 8 + i;
            float2 acc = bb2;
            for (int e = beg; e < end; ++e) {
                int2 q = p1[e];
                if (((q.x >> 17) & (BN - 1)) == nl) {
                    unsigned u = xwb[(q.x & 0x1FFFF) * 64 + lane];
                    float v = __int_as_float(q.y);
                    acc.x += v * __uint_as_float(u << 16);
                    acc.y += v * __uint_as_float(u & 0xffff0000u);
                }
            }
            *(float2*)&out[(long long)(bk * BN + nl) * OUT_CH + lane * 2] = acc;
        }
    }
}

extern "C" void kernel_launch(void* const* d_in, const int* in_sizes, int n_in,
                              void* d_out, int out_size, void* d_ws, size_t ws_size,
                              hipStream_t stream) {
    const float* x     = (const float*)d_in[0];
    const int*   esrc  = (const int*)d_in[1];
    const int*   edst  = (const int*)d_in[2];
    const float* evals = (const float*)d_in[3];
    const float* w     = (const float*)d_in[4];
    const float* bias  = (const float*)d_in[5];
    float* out = (float*)d_out;

    char* ws = (char*)d_ws;
    unsigned*       xwb = (unsigned*)      (ws + OFF_XWB);
    unsigned short* wbf = (unsigned short*)(ws + OFF_WBF);
    int*            cntT= (int*)           (ws + OFF_CNTT);
    int*            rpT = (int*)           (ws + OFF_RPT);
    int*            tot = (int*)           (ws + OFF_TOT);
    int*            bb  = (int*)           (ws + OFF_BB);
    int2*           p1  = (int2*)          (ws + OFF_P1);

    wcvt_h1_kernel<<<NBLK1, 1024, 0, stream>>>(w, wbf, esrc, cntT, tot);
    gemm_kernel<<<(N_NODES + 63) / 64, 256, 0, stream>>>(x, wbf, xwb);
    scan_lb_kernel<<<256, 256, 0, stream>>>(cntT, tot, rpT, bb);
    b1_kernel<<<NBLK1, 1024, 0, stream>>>(esrc, edst, evals, rpT, p1);
    agg_fused_kernel<<<NBIN, 256, 0, stream>>>(bb, p1, xwb, bias, out);
}